// Round 1
// 3206.922 us; speedup vs baseline: 1.1216x; 1.1216x over previous
//
#include <hip/hip_runtime.h>
#include <hip/hip_bf16.h>

#define K_ITERS 20
#define F_IN 512
#define F_HID 128
#define F_OUT 40
#define SCAN_CHUNK 512

// Dataset is FP32 end-to-end (established round 3/6). Output buffer fp32 (16 MB).
// R7 changes:
//  - k_mlp: dropped xs[] LDS tile; x rows read via wave-uniform addresses ->
//    s_load (scalar cache pipe) instead of 8 ds_read broadcasts per k.
//    16 nodes/block (2 half-waves x 8 nodes) halves W1 L2 traffic; LDS 28.4KB
//    -> 5 blocks/CU (occupancy 17%->~62%).
//  - k_prop: blockDim=64, node=blockIdx.x so csr_src/csr_norm chunk loads are
//    compiler-provably uniform -> s_load_dwordx8; vmem instrs drop 3/edge -> 1/edge.
//    Manual double-buffer of csr chunks hides K$ latency under gathers.

// ---------- in-degree histogram over col (targets) ----------
__global__ void k_hist(const int* __restrict__ col, int E, int* __restrict__ cnt){
  int e = blockIdx.x*blockDim.x + threadIdx.x;
  if (e < E) atomicAdd(&cnt[col[e]], 1);
}

// ---------- dinv = rsqrt(in_deg + 1) ----------
__global__ void k_dinv(const int* __restrict__ cnt, int N, float* __restrict__ dinv){
  int i = blockIdx.x*blockDim.x + threadIdx.x;
  if (i < N) dinv[i] = rsqrtf((float)(cnt[i] + 1));
}

// ---------- scan phase 1 ----------
__global__ void k_scan1(const int* __restrict__ cnt, int N, int* __restrict__ bsum){
  __shared__ int sd[256];
  int base = blockIdx.x * SCAN_CHUNK;
  int t = threadIdx.x;
  int i0 = base + 2*t, i1 = i0+1;
  int s = ((i0<N)?cnt[i0]:0) + ((i1<N)?cnt[i1]:0);
  sd[t] = s; __syncthreads();
  for (int off=1; off<256; off<<=1){
    int v = (t>=off)? sd[t-off] : 0;
    __syncthreads();
    sd[t] += v;
    __syncthreads();
  }
  if (t==255) bsum[blockIdx.x] = sd[255];
}
// ---------- scan phase 2 ----------
__global__ void k_scan2(const int* __restrict__ bsum, int NB, int* __restrict__ boff,
                        int* __restrict__ row_ptr, int N, int E){
  __shared__ int sd[256];
  int t = threadIdx.x;
  int v = (t < NB) ? bsum[t] : 0;
  sd[t] = v; __syncthreads();
  for (int off=1; off<256; off<<=1){
    int u = (t>=off)? sd[t-off] : 0;
    __syncthreads();
    sd[t] += u;
    __syncthreads();
  }
  if (t < NB) boff[t] = sd[t] - v;
  if (t == 0) row_ptr[N] = E;
}
// ---------- scan phase 3 ----------
__global__ void k_scan3(const int* __restrict__ cnt, int N, const int* __restrict__ boff,
                        int* __restrict__ row_ptr){
  __shared__ int sd[256];
  int base = blockIdx.x * SCAN_CHUNK;
  int t = threadIdx.x;
  int i0 = base + 2*t, i1 = i0+1;
  int c0 = (i0<N)?cnt[i0]:0, c1 = (i1<N)?cnt[i1]:0;
  int s = c0+c1;
  sd[t] = s; __syncthreads();
  for (int off=1; off<256; off<<=1){
    int v = (t>=off)? sd[t-off] : 0;
    __syncthreads();
    sd[t] += v;
    __syncthreads();
  }
  int excl = sd[t] - s + boff[blockIdx.x];
  if (i0<N) row_ptr[i0] = excl;
  if (i1<N) row_ptr[i1] = excl + c0;
}

// ---------- CSR scatter by target ----------
__global__ void k_scatter(const int* __restrict__ row, const int* __restrict__ col, int E,
                          const int* __restrict__ row_ptr, int* __restrict__ cur,
                          const float* __restrict__ dinv,
                          int* __restrict__ csr_src, float* __restrict__ csr_norm){
  int e = blockIdx.x*blockDim.x + threadIdx.x;
  if (e >= E) return;
  int r = row[e], c = col[e];
  int p = row_ptr[c] + atomicAdd(&cur[c], 1);
  csr_src[p] = r;
  csr_norm[p] = dinv[r]*dinv[c];
}

// ---------- fused MLP: x rows via scalar cache, W1 via coalesced L2 loads ----------
// 256 threads, 16 nodes/block. hid = t&127 owns one hidden unit; half = t>>7
// (readfirstlane-pinned so the compiler can prove x-row addresses wave-uniform
// -> s_load_dwordx4) owns nodes [half*8, half*8+8).
__global__ __launch_bounds__(256) void k_mlp(const float* __restrict__ x,
                      const float* __restrict__ W1, const float* __restrict__ b1,
                      const float* __restrict__ W2, const float* __restrict__ b2,
                      float* __restrict__ h0, int N){
  __shared__ float h1t[16][F_HID];   // 8 KB
  __shared__ float w2s[F_HID*F_OUT]; // 20 KB
  __shared__ float b2s[F_OUT];
  const int t   = threadIdx.x;
  const int hid = t & 127;
  const int half = __builtin_amdgcn_readfirstlane(t >> 7);  // 0 or 1, wave-uniform
  const int nb  = blockIdx.x * 16;

  for (int i = t; i < F_HID*F_OUT; i += 256) w2s[i] = W2[i];
  if (t < F_OUT) b2s[t] = b2[t];

  // clamped row pointers (uniform -> SGPR pairs)
  const float* rp[8];
  #pragma unroll
  for (int n = 0; n < 8; n++){
    int r = nb + half*8 + n;
    if (r >= N) r = N - 1;
    rp[n] = x + (size_t)r * F_IN;
  }

  float acc[8];
  const float bb = b1[hid];
  #pragma unroll
  for (int n = 0; n < 8; n++) acc[n] = bb;

  #pragma unroll 4
  for (int k = 0; k < F_IN; k++){
    const float w = W1[k*F_HID + hid];   // coalesced, L2-resident (256 KB)
    #pragma unroll
    for (int n = 0; n < 8; n++) acc[n] += rp[n][k] * w;  // rp[n][k] uniform -> s_load
  }

  #pragma unroll
  for (int n = 0; n < 8; n++) h1t[half*8 + n][hid] = fmaxf(acc[n], 0.f);
  __syncthreads();

  for (int i = t; i < 16*F_OUT; i += 256){
    const int node = i / F_OUT, c = i - node*F_OUT;
    float a = b2s[c];
    #pragma unroll 4
    for (int k = 0; k < F_HID; k++)
      a += h1t[node][k] * w2s[k*F_OUT + c];
    const int gn = nb + node;
    if (gn < N) h0[(size_t)gn*F_OUT + c] = fmaxf(a, 0.f);
  }
}

// ---------- propagation: z' = 0.9*(A_hat z) + 0.1*h0 ----------
// One 64-thread block per node (node = blockIdx.x) so csr chunk addresses are
// compiler-provably wave-uniform -> s_load_dwordx8 on the scalar pipe.
// Only the z-row gather (1 vmem instr/edge, 160B coalesced) stays on vmem.
// csr chunks double-buffered: next chunk's s_loads issue before the current
// gathers are waited on.
__global__ __launch_bounds__(64) void k_prop(const int* __restrict__ row_ptr, const int* __restrict__ csr_src,
                      const float* __restrict__ csr_norm, const float* __restrict__ dinv,
                      const float* __restrict__ zin, const float* __restrict__ h0,
                      float* __restrict__ zout, int N){
  const int node = blockIdx.x;
  const int lane = threadIdx.x;
  if (lane >= F_OUT) return;
  const int beg = row_ptr[node], end = row_ptr[node+1];
  float acc = 0.f;
  int p = beg;

  int   cs[8]; float cn[8];
  bool have = (p + 8 <= end);
  if (have){
    #pragma unroll
    for (int j = 0; j < 8; j++){ cs[j] = csr_src[p+j]; cn[j] = csr_norm[p+j]; }
  }
  while (have){
    const int np = p + 8;
    const bool nh = (np + 8 <= end);
    int ns[8]; float nn[8];
    if (nh){
      #pragma unroll
      for (int j = 0; j < 8; j++){ ns[j] = csr_src[np+j]; nn[j] = csr_norm[np+j]; }
    }
    float z[8];
    #pragma unroll
    for (int j = 0; j < 8; j++) z[j] = zin[(size_t)cs[j]*F_OUT + lane];
    #pragma unroll
    for (int j = 0; j < 8; j++) acc += cn[j]*z[j];
    p = np; have = nh;
    if (nh){
      #pragma unroll
      for (int j = 0; j < 8; j++){ cs[j] = ns[j]; cn[j] = nn[j]; }
    }
  }
  for (; p < end; ++p)
    acc += csr_norm[p] * zin[(size_t)csr_src[p]*F_OUT + lane];

  const float di = dinv[node];
  const size_t idx = (size_t)node*F_OUT + lane;
  acc += di*di*zin[idx];
  zout[idx] = 0.9f*acc + 0.1f*h0[idx];
}

extern "C" void kernel_launch(void* const* d_in, const int* in_sizes, int n_in,
                              void* d_out, int out_size, void* d_ws, size_t ws_size,
                              hipStream_t stream){
  const float* x  = (const float*)d_in[0];
  const int*   ei = (const int*)d_in[1];
  const float* W1 = (const float*)d_in[2];
  const float* b1 = (const float*)d_in[3];
  const float* W2 = (const float*)d_in[4];
  const float* b2 = (const float*)d_in[5];
  int N = in_sizes[0] / F_IN;
  int E = in_sizes[1] / 2;
  const int* row = ei;       // sources
  const int* col = ei + E;   // targets

  char* w = (char*)d_ws;
  auto alloc = [&](size_t bytes)->void*{ void* p = w; w += (bytes + 255) & ~255ull; return p; };
  int*   cnt      = (int*)  alloc((size_t)N*4);
  int*   cur      = (int*)  alloc((size_t)N*4);
  int*   row_ptr  = (int*)  alloc(((size_t)N+1)*4);
  float* dinv     = (float*)alloc((size_t)N*4);
  int NB = (N + SCAN_CHUNK-1)/SCAN_CHUNK;   // 196 for N=100000 (<=256)
  int*   bsum     = (int*)  alloc((size_t)NB*4);
  int*   boff     = (int*)  alloc((size_t)NB*4);
  int*   csr_src  = (int*)  alloc((size_t)E*4);
  float* csr_norm = (float*)alloc((size_t)E*4);
  float* h0       = (float*)alloc((size_t)N*F_OUT*4);
  float* zA       = (float*)alloc((size_t)N*F_OUT*4);
  float* zB       = (float*)alloc((size_t)N*F_OUT*4);

  (void)hipMemsetAsync(cnt, 0, (size_t)N*4, stream);
  (void)hipMemsetAsync(cur, 0, (size_t)N*4, stream);

  int ge = (E + 255)/256;
  k_hist   <<<ge, 256, 0, stream>>>(col, E, cnt);
  k_dinv   <<<(N+255)/256, 256, 0, stream>>>(cnt, N, dinv);
  k_scan1  <<<NB, 256, 0, stream>>>(cnt, N, bsum);
  k_scan2  <<<1, 256, 0, stream>>>(bsum, NB, boff, row_ptr, N, E);
  k_scan3  <<<NB, 256, 0, stream>>>(cnt, N, boff, row_ptr);
  k_scatter<<<ge, 256, 0, stream>>>(row, col, E, row_ptr, cur, dinv, csr_src, csr_norm);

  k_mlp<<<(N+15)/16, 256, 0, stream>>>(x, W1, b1, W2, b2, h0, N);

  float* zi = h0; float* zo = zA;
  for (int it=0; it<K_ITERS; ++it){
    float* dst = (it == K_ITERS-1) ? (float*)d_out : zo;   // final iter writes output
    k_prop<<<N, 64, 0, stream>>>(row_ptr, csr_src, csr_norm, dinv, zi, h0, dst, N);
    float* nxt = (it==0) ? zB : zi;
    zi = zo; zo = nxt;
  }
}

// Round 2
// 2850.605 us; speedup vs baseline: 1.2618x; 1.1250x over previous
//
#include <hip/hip_runtime.h>
#include <hip/hip_bf16.h>

#define K_ITERS 20
#define F_IN 512
#define F_HID 128
#define F_OUT 40
#define SCAN_CHUNK 512

// Dataset is FP32 end-to-end (established round 3/6). Output buffer fp32 (16 MB).
// R8 changes:
//  - k_mlp: x via wave-uniform VECTOR loads (asm-laundered ptrs defeat
//    scalarization; 1 L1 request broadcast to lanes). W1 k-tiles double-buffered
//    in LDS via global_load_lds(16B), read as conflict-free ds_read_b128.
//    8n x 4h per-thread tile -> VALU-bound. GEMM2: h1 transposed [128][68] in
//    LDS (conflict-free b32), lane=node (64/64 lanes active), W2 via s_load.
//  - k_prop: 4 nodes per 256-thread block (wave per node, readfirstlane wave id
//    keeps csr s_loads scalar) -> 32 waves/CU vs 16 with 64-thread blocks.

typedef const float __attribute__((address_space(1)))* glb_fp;
typedef float __attribute__((address_space(3)))* lds_fp;

// ---------- in-degree histogram over col (targets) ----------
__global__ void k_hist(const int* __restrict__ col, int E, int* __restrict__ cnt){
  int e = blockIdx.x*blockDim.x + threadIdx.x;
  if (e < E) atomicAdd(&cnt[col[e]], 1);
}

// ---------- dinv = rsqrt(in_deg + 1) ----------
__global__ void k_dinv(const int* __restrict__ cnt, int N, float* __restrict__ dinv){
  int i = blockIdx.x*blockDim.x + threadIdx.x;
  if (i < N) dinv[i] = rsqrtf((float)(cnt[i] + 1));
}

// ---------- scan phase 1 ----------
__global__ void k_scan1(const int* __restrict__ cnt, int N, int* __restrict__ bsum){
  __shared__ int sd[256];
  int base = blockIdx.x * SCAN_CHUNK;
  int t = threadIdx.x;
  int i0 = base + 2*t, i1 = i0+1;
  int s = ((i0<N)?cnt[i0]:0) + ((i1<N)?cnt[i1]:0);
  sd[t] = s; __syncthreads();
  for (int off=1; off<256; off<<=1){
    int v = (t>=off)? sd[t-off] : 0;
    __syncthreads();
    sd[t] += v;
    __syncthreads();
  }
  if (t==255) bsum[blockIdx.x] = sd[255];
}
// ---------- scan phase 2 ----------
__global__ void k_scan2(const int* __restrict__ bsum, int NB, int* __restrict__ boff,
                        int* __restrict__ row_ptr, int N, int E){
  __shared__ int sd[256];
  int t = threadIdx.x;
  int v = (t < NB) ? bsum[t] : 0;
  sd[t] = v; __syncthreads();
  for (int off=1; off<256; off<<=1){
    int u = (t>=off)? sd[t-off] : 0;
    __syncthreads();
    sd[t] += u;
    __syncthreads();
  }
  if (t < NB) boff[t] = sd[t] - v;
  if (t == 0) row_ptr[N] = E;
}
// ---------- scan phase 3 ----------
__global__ void k_scan3(const int* __restrict__ cnt, int N, const int* __restrict__ boff,
                        int* __restrict__ row_ptr){
  __shared__ int sd[256];
  int base = blockIdx.x * SCAN_CHUNK;
  int t = threadIdx.x;
  int i0 = base + 2*t, i1 = i0+1;
  int c0 = (i0<N)?cnt[i0]:0, c1 = (i1<N)?cnt[i1]:0;
  int s = c0+c1;
  sd[t] = s; __syncthreads();
  for (int off=1; off<256; off<<=1){
    int v = (t>=off)? sd[t-off] : 0;
    __syncthreads();
    sd[t] += v;
    __syncthreads();
  }
  int excl = sd[t] - s + boff[blockIdx.x];
  if (i0<N) row_ptr[i0] = excl;
  if (i1<N) row_ptr[i1] = excl + c0;
}

// ---------- CSR scatter by target ----------
__global__ void k_scatter(const int* __restrict__ row, const int* __restrict__ col, int E,
                          const int* __restrict__ row_ptr, int* __restrict__ cur,
                          const float* __restrict__ dinv,
                          int* __restrict__ csr_src, float* __restrict__ csr_norm){
  int e = blockIdx.x*blockDim.x + threadIdx.x;
  if (e >= E) return;
  int r = row[e], c = col[e];
  int p = row_ptr[c] + atomicAdd(&cur[c], 1);
  csr_src[p] = r;
  csr_norm[p] = dinv[r]*dinv[c];
}

// ---------- fused MLP ----------
// 256 threads, 64 nodes/block. GEMM1: th=t&31 owns hids th*4..+3, tn=t>>5 owns
// nodes tn*8..+7. x via laundered uniform vector loads; W1 via LDS dbuf.
__global__ __launch_bounds__(256) void k_mlp(const float* __restrict__ x,
                      const float* __restrict__ W1, const float* __restrict__ b1,
                      const float* __restrict__ W2, const float* __restrict__ b2,
                      float* __restrict__ h0, int N){
  __shared__ float lds[8704];        // union: W1 dbuf 2x16KB | h1tT[128][68] 34.8KB
  const int t    = threadIdx.x;
  const int th   = t & 31;
  const int tn   = t >> 5;
  const int lane = t & 63;
  const int wv   = __builtin_amdgcn_readfirstlane(t >> 6);   // 0..3
  const int nb   = blockIdx.x * 64;

  // laundered x row pointers: force VGPR so compiler emits vector loads
  // (uniform address -> single L1 request broadcast to all lanes)
  const float* xp[8];
  #pragma unroll
  for (int j=0;j<8;++j){
    int r = nb + tn*8 + j; if (r >= N) r = N-1;
    const float* p = x + (size_t)r * F_IN;
    asm volatile("" : "+v"(p));
    xp[j] = p;
  }

  // stage W1 k-tile kt (32 rows x 128 = 16KB, contiguous) into buffer b
  auto stage = [&](int kt, int b){
    const float* gs = W1 + kt*(32*128) + wv*1024 + lane*4;
    int lo = __builtin_amdgcn_readfirstlane((b*4096 + wv*1024) * 4); // bytes
    #pragma unroll
    for (int i=0;i<4;++i){
      __builtin_amdgcn_global_load_lds((glb_fp)(gs + i*256),
        (lds_fp)((char*)lds + lo + i*1024), 16, 0, 0);
    }
  };

  float acc[8][4];
  {
    float4 bb = *(const float4*)(b1 + th*4);
    #pragma unroll
    for (int j=0;j<8;++j){ acc[j][0]=bb.x; acc[j][1]=bb.y; acc[j][2]=bb.z; acc[j][3]=bb.w; }
  }

  stage(0, 0);
  __syncthreads();

  for (int kt=0; kt<16; ++kt){
    const int cur = kt & 1;
    if (kt < 15) stage(kt+1, cur^1);
    const int kbase = kt*32;
    #pragma unroll
    for (int c=0;c<8;++c){
      const int kb = kbase + c*4;
      float4 xv[8];
      #pragma unroll
      for (int j=0;j<8;++j) xv[j] = *(const float4*)(xp[j] + kb);
      const float* wl = lds + cur*4096 + c*512 + th*4;
      float4 wa = *(const float4*)(wl);
      float4 wb = *(const float4*)(wl + 128);
      float4 wc = *(const float4*)(wl + 256);
      float4 wd = *(const float4*)(wl + 384);
      #pragma unroll
      for (int j=0;j<8;++j){
        acc[j][0] += xv[j].x*wa.x; acc[j][1] += xv[j].x*wa.y; acc[j][2] += xv[j].x*wa.z; acc[j][3] += xv[j].x*wa.w;
        acc[j][0] += xv[j].y*wb.x; acc[j][1] += xv[j].y*wb.y; acc[j][2] += xv[j].y*wb.z; acc[j][3] += xv[j].y*wb.w;
        acc[j][0] += xv[j].z*wc.x; acc[j][1] += xv[j].z*wc.y; acc[j][2] += xv[j].z*wc.z; acc[j][3] += xv[j].z*wc.w;
        acc[j][0] += xv[j].w*wd.x; acc[j][1] += xv[j].w*wd.y; acc[j][2] += xv[j].w*wd.z; acc[j][3] += xv[j].w*wd.w;
      }
    }
    __syncthreads();
  }

  // relu + write h1 transposed: h1tT[hid][node], pad 68 (conflict-free reads)
  #pragma unroll
  for (int h=0; h<4; ++h){
    const int hid = th*4 + h;
    float4 v0 = make_float4(fmaxf(acc[0][h],0.f), fmaxf(acc[1][h],0.f),
                            fmaxf(acc[2][h],0.f), fmaxf(acc[3][h],0.f));
    float4 v1 = make_float4(fmaxf(acc[4][h],0.f), fmaxf(acc[5][h],0.f),
                            fmaxf(acc[6][h],0.f), fmaxf(acc[7][h],0.f));
    *(float4*)&lds[hid*68 + tn*8]     = v0;
    *(float4*)&lds[hid*68 + tn*8 + 4] = v1;
  }
  __syncthreads();

  // GEMM2: wave wv owns cols wv*10..+9; lane = node (all 64 lanes active).
  // h1 via conflict-free LDS b32; W2 via uniform s_load (K$-resident 20KB).
  const int c0 = wv*10;
  float a2[10];
  #pragma unroll
  for (int i=0;i<10;++i) a2[i] = b2[c0+i];
  #pragma unroll 4
  for (int k=0;k<F_HID;++k){
    const float hv = lds[k*68 + lane];
    #pragma unroll
    for (int i=0;i<10;++i) a2[i] += hv * W2[k*F_OUT + c0 + i];
  }
  const int gn = nb + lane;
  if (gn < N){
    float* o = h0 + (size_t)gn*F_OUT + c0;
    #pragma unroll
    for (int i=0;i<10;++i) o[i] = fmaxf(a2[i], 0.f);
  }
}

// ---------- propagation: z' = 0.9*(A_hat z) + 0.1*h0 ----------
// 4 nodes per 256-thread block (one wave each) -> 32 waves/CU occupancy.
// readfirstlane wave id keeps node wave-uniform -> csr chunk loads stay s_load.
__global__ __launch_bounds__(256) void k_prop(const int* __restrict__ row_ptr, const int* __restrict__ csr_src,
                      const float* __restrict__ csr_norm, const float* __restrict__ dinv,
                      const float* __restrict__ zin, const float* __restrict__ h0,
                      float* __restrict__ zout, int N){
  const int wv   = __builtin_amdgcn_readfirstlane((int)(threadIdx.x >> 6));
  const int node = blockIdx.x*4 + wv;
  const int lane = threadIdx.x & 63;
  if (node >= N) return;
  if (lane >= F_OUT) return;
  const int beg = row_ptr[node], end = row_ptr[node+1];
  float acc = 0.f;
  int p = beg;

  int   cs[8]; float cn[8];
  bool have = (p + 8 <= end);
  if (have){
    #pragma unroll
    for (int j = 0; j < 8; j++){ cs[j] = csr_src[p+j]; cn[j] = csr_norm[p+j]; }
  }
  while (have){
    const int np = p + 8;
    const bool nh = (np + 8 <= end);
    int ns[8]; float nn[8];
    if (nh){
      #pragma unroll
      for (int j = 0; j < 8; j++){ ns[j] = csr_src[np+j]; nn[j] = csr_norm[np+j]; }
    }
    float z[8];
    #pragma unroll
    for (int j = 0; j < 8; j++) z[j] = zin[(size_t)cs[j]*F_OUT + lane];
    #pragma unroll
    for (int j = 0; j < 8; j++) acc += cn[j]*z[j];
    p = np; have = nh;
    if (nh){
      #pragma unroll
      for (int j = 0; j < 8; j++){ cs[j] = ns[j]; cn[j] = nn[j]; }
    }
  }
  for (; p < end; ++p)
    acc += csr_norm[p] * zin[(size_t)csr_src[p]*F_OUT + lane];

  const float di = dinv[node];
  const size_t idx = (size_t)node*F_OUT + lane;
  acc += di*di*zin[idx];
  zout[idx] = 0.9f*acc + 0.1f*h0[idx];
}

extern "C" void kernel_launch(void* const* d_in, const int* in_sizes, int n_in,
                              void* d_out, int out_size, void* d_ws, size_t ws_size,
                              hipStream_t stream){
  const float* x  = (const float*)d_in[0];
  const int*   ei = (const int*)d_in[1];
  const float* W1 = (const float*)d_in[2];
  const float* b1 = (const float*)d_in[3];
  const float* W2 = (const float*)d_in[4];
  const float* b2 = (const float*)d_in[5];
  int N = in_sizes[0] / F_IN;
  int E = in_sizes[1] / 2;
  const int* row = ei;       // sources
  const int* col = ei + E;   // targets

  char* w = (char*)d_ws;
  auto alloc = [&](size_t bytes)->void*{ void* p = w; w += (bytes + 255) & ~255ull; return p; };
  int*   cnt      = (int*)  alloc((size_t)N*4);
  int*   cur      = (int*)  alloc((size_t)N*4);
  int*   row_ptr  = (int*)  alloc(((size_t)N+1)*4);
  float* dinv     = (float*)alloc((size_t)N*4);
  int NB = (N + SCAN_CHUNK-1)/SCAN_CHUNK;   // 196 for N=100000 (<=256)
  int*   bsum     = (int*)  alloc((size_t)NB*4);
  int*   boff     = (int*)  alloc((size_t)NB*4);
  int*   csr_src  = (int*)  alloc((size_t)E*4);
  float* csr_norm = (float*)alloc((size_t)E*4);
  float* h0       = (float*)alloc((size_t)N*F_OUT*4);
  float* zA       = (float*)alloc((size_t)N*F_OUT*4);
  float* zB       = (float*)alloc((size_t)N*F_OUT*4);

  (void)hipMemsetAsync(cnt, 0, (size_t)N*4, stream);
  (void)hipMemsetAsync(cur, 0, (size_t)N*4, stream);

  int ge = (E + 255)/256;
  k_hist   <<<ge, 256, 0, stream>>>(col, E, cnt);
  k_dinv   <<<(N+255)/256, 256, 0, stream>>>(cnt, N, dinv);
  k_scan1  <<<NB, 256, 0, stream>>>(cnt, N, bsum);
  k_scan2  <<<1, 256, 0, stream>>>(bsum, NB, boff, row_ptr, N, E);
  k_scan3  <<<NB, 256, 0, stream>>>(cnt, N, boff, row_ptr);
  k_scatter<<<ge, 256, 0, stream>>>(row, col, E, row_ptr, cur, dinv, csr_src, csr_norm);

  k_mlp<<<(N+63)/64, 256, 0, stream>>>(x, W1, b1, W2, b2, h0, N);

  float* zi = h0; float* zo = zA;
  int gp = (N + 3)/4;
  for (int it=0; it<K_ITERS; ++it){
    float* dst = (it == K_ITERS-1) ? (float*)d_out : zo;   // final iter writes output
    k_prop<<<gp, 256, 0, stream>>>(row_ptr, csr_src, csr_norm, dinv, zi, h0, dst, N);
    float* nxt = (it==0) ? zB : zi;
    zi = zo; zo = nxt;
  }
}